// Round 1
// baseline (3062.815 us; speedup 1.0000x reference)
//
#include <hip/hip_runtime.h>
#include <stdint.h>

// Problem constants (fixed seed, fixed shapes)
#define BB 16
#define TT 2048
#define NI 32
#define NN 2048
#define NO 32
#define WASH 64
#define TO (TT - WASH + 1)   // 1985
#define W 24                 // ELL width (max degree; Poisson(6) tail makes >24 impossible in practice)
#define CH 16                // time-chunk for fused MFMA GEMMs
#define UST 18               // u_lds row stride (halfwords), odd*9 banks -> conflict-free-ish
#define HBST 2056            // hb row stride (halfwords) = 2048 + 8 padding

typedef short bfvec __attribute__((ext_vector_type(8)));   // 8 bf16 in 4 VGPRs
typedef float f4_t  __attribute__((ext_vector_type(4)));

__device__ inline unsigned short f2bf(float f) {
  unsigned int u = __builtin_bit_cast(unsigned int, f);
  unsigned int r = u + 0x7fffu + ((u >> 16) & 1u);   // RNE
  return (unsigned short)(r >> 16);
}
__device__ inline float bf2f(unsigned short s) {
  unsigned int u = ((unsigned int)s) << 16;
  return __builtin_bit_cast(float, u);
}
__device__ inline float tanh_fast(float x) {
  x = fminf(15.f, fmaxf(-15.f, x));
  float e = __expf(x + x);
  return (e - 1.0f) / (e + 1.0f);
}

// ---------------- K1: dense A -> packed ELL (bf16 val << 16 | byte-offset col) ----------------
__global__ void build_ell(const float* __restrict__ A, uint32_t* __restrict__ ell,
                          uint32_t* __restrict__ deg) {
  int gw = (int)((blockIdx.x * blockDim.x + threadIdx.x) >> 6);  // one wave per row
  int lane = (int)(threadIdx.x & 63);
  if (gw >= NN) return;
  const float* row = A + (size_t)gw * NN;
  int base = 0;
  for (int c = 0; c < NN; c += 64) {
    float v = row[c + lane];
    bool nz = (v != 0.0f);
    unsigned long long mask = __ballot(nz);
    int pre = __popcll(mask & ((1ull << lane) - 1ull));
    if (nz) {
      int idx = base + pre;
      if (idx < W) {
        uint32_t packed = (((uint32_t)f2bf(v)) << 16) | (uint32_t)((c + lane) * 4);
        ell[(size_t)gw * W + idx] = packed;
      }
    }
    base += __popcll(mask);
  }
  int d = base < W ? base : W;
  if (lane == 0) deg[gw] = (uint32_t)d;
  for (int k = d + lane; k < W; k += 64) ell[(size_t)gw * W + k] = 0u;  // val=0, col=0 padding
}

// ---------------- K2: counting sort rows by degree -> perm ----------------
__global__ void sortperm(const uint32_t* __restrict__ deg, uint32_t* __restrict__ perm) {
  __shared__ unsigned int hist[32];
  __shared__ unsigned int off[32];
  int tid = (int)threadIdx.x;
  if (tid < 32) hist[tid] = 0;
  __syncthreads();
  for (int r = tid; r < NN; r += 1024) {
    unsigned int d = deg[r]; if (d > 31u) d = 31u;
    atomicAdd(&hist[d], 1u);
  }
  __syncthreads();
  if (tid == 0) {
    unsigned int s = 0;
    for (int i = 0; i < 32; ++i) { off[i] = s; s += hist[i]; }
  }
  __syncthreads();
  for (int r = tid; r < NN; r += 1024) {
    unsigned int d = deg[r]; if (d > 31u) d = 31u;
    unsigned int p = atomicAdd(&off[d], 1u);
    perm[p] = (uint32_t)r;
  }
}

// ---------------- K3: Win/Wout -> MFMA B-fragment order (bf16 pairs) ----------------
__global__ void build_frags(const float* __restrict__ Win, const float* __restrict__ Wout,
                            uint32_t* __restrict__ winf, uint32_t* __restrict__ woutf) {
  int f = (int)(blockIdx.x * blockDim.x + threadIdx.x);  // 0..65535
  if (f < 32768) {
    // u-GEMM B: B[k=i][col=n] = Win[n][i]; tile ntg (0..127), word=(ntg*64+lane)*4+reg
    int reg = f & 3, lane = (f >> 2) & 63, ntg = f >> 8;
    int n = (ntg << 4) + (lane & 15);
    int k = ((lane >> 4) << 3) + reg * 2;
    uint32_t lo = f2bf(Win[(size_t)n * NI + k]);
    uint32_t hi = f2bf(Win[(size_t)n * NI + k + 1]);
    winf[f] = lo | (hi << 16);
  } else {
    // out-GEMM B: B[k=n][col=o] = Wout[o][n]; word=((ot*64+kt)*64+lane)*4+reg
    int g = f - 32768;
    int reg = g & 3, lane = (g >> 2) & 63, kt = (g >> 8) & 63, ot = g >> 14;
    int o = (ot << 4) + (lane & 15);
    int n = (kt << 5) + ((lane >> 4) << 3) + reg * 2;
    uint32_t lo = f2bf(Wout[(size_t)o * NN + n]);
    uint32_t hi = f2bf(Wout[(size_t)o * NN + n + 1]);
    woutf[g] = lo | (hi << 16);
  }
}

// ---------------- K4: fused recurrence (1 workgroup per batch) ----------------
// LDS: h_a[2048]f32 | h_b[2048]f32 | u[2048][UST]bf16 (overlaid by out-scratch) | hb[CH][HBST]bf16
__global__ __launch_bounds__(1024, 1) void rec_kernel(
    const float* __restrict__ x, const uint32_t* __restrict__ ell,
    const uint32_t* __restrict__ deg, const uint32_t* __restrict__ perm,
    const uint32_t* __restrict__ winf, const uint32_t* __restrict__ woutf,
    float* __restrict__ out) {
  extern __shared__ char smem[];
  float* h_a = (float*)smem;                       //  8192 B
  float* h_b = (float*)(smem + 8192);              //  8192 B
  unsigned short* u_lds = (unsigned short*)(smem + 16384);   // 73728 B
  float* oscratch = (float*)(smem + 16384);                  // overlay (32768 B used)
  unsigned short* hb = (unsigned short*)(smem + 16384 + 73728); // 65792 B  (total 155904)

  const int tid = (int)threadIdx.x;
  const int b = (int)blockIdx.x;
  const int lane = tid & 63;
  const int wv = tid >> 6;

  const int r0 = (int)perm[tid];
  const int r1 = (int)perm[2047 - tid];
  int d0 = (int)deg[r0], d1 = (int)deg[r1];
  int m0 = d0, m1 = d1;
  #pragma unroll
  for (int off = 32; off; off >>= 1) {
    m0 = max(m0, __shfl_xor(m0, off));
    m1 = max(m1, __shfl_xor(m1, off));
  }
  m0 = __builtin_amdgcn_readfirstlane(m0);
  m1 = __builtin_amdgcn_readfirstlane(m1);

  // ELL rows into registers (static-indexed after full unroll)
  uint32_t e0[W], e1[W];
  {
    const uint4* p0 = (const uint4*)(ell + (size_t)r0 * W);
    const uint4* p1 = (const uint4*)(ell + (size_t)r1 * W);
    #pragma unroll
    for (int q = 0; q < W / 4; ++q) {
      uint4 a = p0[q]; uint4 c = p1[q];
      e0[q*4+0]=a.x; e0[q*4+1]=a.y; e0[q*4+2]=a.z; e0[q*4+3]=a.w;
      e1[q*4+0]=c.x; e1[q*4+1]=c.y; e1[q*4+2]=c.z; e1[q*4+3]=c.w;
    }
  }

  h_a[tid] = 0.0f; h_a[tid + 1024] = 0.0f;
  float h0 = 0.0f, h1 = 0.0f;

  const int la15 = lane & 15;
  const int lg = lane >> 4;

  auto step = [&](int tt, const float* hcur, float* hnxt) {
    float y0 = bf2f(u_lds[(size_t)r0 * UST + tt]);
    float y1 = bf2f(u_lds[(size_t)r1 * UST + tt]);
    #pragma unroll
    for (int k = 0; k < W; ++k) {
      if (k >= m0) break;
      uint32_t e = e0[k];
      float v = __builtin_bit_cast(float, e & 0xffff0000u);
      float hv = *(const float*)((const char*)hcur + (e & 0xffffu));
      y0 = __builtin_fmaf(v, hv, y0);
    }
    #pragma unroll
    for (int k = 0; k < W; ++k) {
      if (k >= m1) break;
      uint32_t e = e1[k];
      float v = __builtin_bit_cast(float, e & 0xffff0000u);
      float hv = *(const float*)((const char*)hcur + (e & 0xffffu));
      y1 = __builtin_fmaf(v, hv, y1);
    }
    float hn0 = 0.1f * h0 + 0.9f * tanh_fast(y0);
    float hn1 = 0.1f * h1 + 0.9f * tanh_fast(y1);
    hnxt[r0] = hn0; hnxt[r1] = hn1;
    hb[(size_t)tt * HBST + r0] = f2bf(hn0);
    hb[(size_t)tt * HBST + r1] = f2bf(hn1);
    h0 = hn0; h1 = hn1;
    __syncthreads();
  };

  for (int c = 0; c < TT / CH; ++c) {
    const int t0 = c * CH;

    // ---- phase A: u = x_chunk @ Win^T via MFMA; wave wv covers n in [wv*128, wv*128+128)
    {
      const float* xp = x + ((size_t)b * TT + (t0 + la15)) * NI + (lg << 3);
      float4 x0 = *(const float4*)xp;
      float4 x1 = *(const float4*)(xp + 4);
      union { unsigned short u16[8]; bfvec v; } af;
      af.u16[0]=f2bf(x0.x); af.u16[1]=f2bf(x0.y); af.u16[2]=f2bf(x0.z); af.u16[3]=f2bf(x0.w);
      af.u16[4]=f2bf(x1.x); af.u16[5]=f2bf(x1.y); af.u16[6]=f2bf(x1.z); af.u16[7]=f2bf(x1.w);
      #pragma unroll
      for (int nt = 0; nt < 8; ++nt) {
        int ntg = (wv << 3) + nt;
        union { uint4 q; bfvec v; } bw;
        bw.q = *(const uint4*)(winf + (((size_t)ntg * 64 + lane) << 2));
        f4_t acc = {0.f, 0.f, 0.f, 0.f};
        acc = __builtin_amdgcn_mfma_f32_16x16x32_bf16(af.v, bw.v, acc, 0, 0, 0);
        int n = (ntg << 4) + la15;
        int tl = lg << 2;
        uint32_t lo = (uint32_t)f2bf(acc[0]) | ((uint32_t)f2bf(acc[1]) << 16);
        uint32_t hi = (uint32_t)f2bf(acc[2]) | ((uint32_t)f2bf(acc[3]) << 16);
        uint32_t* up = (uint32_t*)(u_lds + (size_t)n * UST + tl);
        up[0] = lo; up[1] = hi;
      }
    }
    __syncthreads();

    // ---- phase B: 16 recurrence steps (double-buffered h, one barrier per step)
    #pragma unroll 1
    for (int tt = 0; tt < CH; tt += 2) {
      step(tt, h_a, h_b);
      step(tt + 1, h_b, h_a);
    }

    // ---- phase C: out_chunk = hb @ Wout^T via MFMA; wave wv covers K in [wv*128, wv*128+128)
    {
      f4_t oa0 = {0.f,0.f,0.f,0.f}, oa1 = {0.f,0.f,0.f,0.f};
      #pragma unroll
      for (int k4 = 0; k4 < 4; ++k4) {
        int kt = (wv << 2) + k4;
        union { uint4 q; bfvec v; } ha, w0, w1;
        ha.q = *(const uint4*)(hb + (size_t)la15 * HBST + (kt << 5) + (lg << 3));
        w0.q = *(const uint4*)(woutf + (((size_t)(kt) * 64 + lane) << 2));
        w1.q = *(const uint4*)(woutf + (((size_t)(64 + kt) * 64 + lane) << 2));
        oa0 = __builtin_amdgcn_mfma_f32_16x16x32_bf16(ha.v, w0.v, oa0, 0, 0, 0);
        oa1 = __builtin_amdgcn_mfma_f32_16x16x32_bf16(ha.v, w1.v, oa1, 0, 0, 0);
      }
      float* os = oscratch + (wv << 9);
      int tb = lg << 2;
      #pragma unroll
      for (int r = 0; r < 4; ++r) os[(tb + r) * 32 + la15] = oa0[r];
      #pragma unroll
      for (int r = 0; r < 4; ++r) os[(tb + r) * 32 + 16 + la15] = oa1[r];
    }
    __syncthreads();
    if (tid < 512) {
      float s = 0.0f;
      #pragma unroll
      for (int w2 = 0; w2 < 16; ++w2) s += oscratch[(w2 << 9) + tid];
      int tg = t0 + (tid >> 5);
      if (tg >= WASH - 1)
        out[((size_t)b * TO + (tg - (WASH - 1))) * NO + (tid & 31)] = s;
    }
    __syncthreads();  // protect u/oscratch before next chunk's phase A
  }
}

extern "C" void kernel_launch(void* const* d_in, const int* in_sizes, int n_in,
                              void* d_out, int out_size, void* d_ws, size_t ws_size,
                              hipStream_t stream) {
  (void)in_sizes; (void)n_in; (void)out_size; (void)ws_size;
  const float* x    = (const float*)d_in[0];
  const float* Win  = (const float*)d_in[1];
  const float* A    = (const float*)d_in[2];
  const float* Wout = (const float*)d_in[3];
  float* out = (float*)d_out;

  char* ws = (char*)d_ws;
  uint32_t* ell   = (uint32_t*)(ws);            // 2048*24*4 = 196608
  uint32_t* deg   = (uint32_t*)(ws + 196608);   // 8192
  uint32_t* perm  = (uint32_t*)(ws + 204800);   // 8192
  uint32_t* winf  = (uint32_t*)(ws + 212992);   // 131072
  uint32_t* woutf = (uint32_t*)(ws + 344064);   // 131072  (total 475136 B)

  hipFuncSetAttribute((const void*)rec_kernel,
                      hipFuncAttributeMaxDynamicSharedMemorySize, 160 * 1024);

  hipLaunchKernelGGL(build_ell, dim3(512), dim3(256), 0, stream, A, ell, deg);
  hipLaunchKernelGGL(sortperm, dim3(1), dim3(1024), 0, stream, deg, perm);
  hipLaunchKernelGGL(build_frags, dim3(256), dim3(256), 0, stream, Win, Wout, winf, woutf);
  hipLaunchKernelGGL(rec_kernel, dim3(16), dim3(1024), 155904, stream,
                     x, ell, deg, perm, winf, woutf, out);
}